// Round 4
// baseline (185.409 us; speedup 1.0000x reference)
//
#include <hip/hip_runtime.h>
#include <cstddef>

// Critic_43104291783486 — round 4: W1/W2 direct global->register B-fragments
// (no LDS round-trip for weights). X stays LDS-staged (shared across waves).
// fp16 MFMA (v_mfma_f32_16x16x32_f16), f32 accumulate. LDS 44KB -> 3 blocks/CU.

#define BN 256   // nodes
#define HD 256   // hidden
#define FD 64    // feature out

#define XS 40    // X lds row stride (fp16): 32 k + 8 pad (80B rows, 16B aligned)
#define HS 264   // h lds row stride (fp16): 256 + 8 pad (528B rows)

typedef _Float16 f16x8 __attribute__((ext_vector_type(8)));
typedef float f32x4 __attribute__((ext_vector_type(4)));

__device__ __forceinline__ f16x8 pack8(const float v[8]) {
  f16x8 r;
#pragma unroll
  for (int i = 0; i < 8; ++i) r[i] = (_Float16)v[i];
  return r;
}

// ---------- X staging: 64 rows x 32 k, fp32 global -> fp16 LDS ----------
// thread t: row = t>>2, k-oct = (t&3)*8; 4 lanes cover 128B contiguous global.
__device__ __forceinline__ void x_load(const float* __restrict__ src, int b0, int n,
                                       int kOff, int tid, float4 xr[2]) {
  int row = tid >> 2, ko = (tid & 3) * 8;
  const float* p = src + (size_t)(b0 + row) * (BN * HD) + n * HD + kOff + ko;
  xr[0] = *(const float4*)p;
  xr[1] = *(const float4*)(p + 4);
}
__device__ __forceinline__ void x_write(_Float16* Xl, int tid, const float4 xr[2]) {
  int row = tid >> 2, ko = (tid & 3) * 8;
  const float* f = (const float*)xr;
  f16x8 v;
#pragma unroll
  for (int i = 0; i < 8; ++i) v[i] = (_Float16)f[i];
  *(f16x8*)(Xl + row * XS + ko) = v;   // 16B-aligned (XS*2 = 80)
}

// ---------- GEMM1: C(64x256) = X(64xK) @ W(Kx256), K = NK*32 ----------
// wave w owns cols w*64..+63 (4 B-frags). B-frag element j (lane l):
// W[kt*32 + (l>>4)*8 + j][Nbase + nf*16 + (l&15)]  -> direct global loads,
// 8 dwords stride 256 floats; per instr 4x64B segments (lanes 0-15 contiguous).
// A-frag from LDS: row = m*16 + (l&15), k contiguous (verified r3 layout).
template <int NK>
__device__ __forceinline__ void run_gemm1(const float* xs0, const float* xs1,
                                          const float* __restrict__ Wg,
                                          int b0, int n, int tid, int lrow, int lk,
                                          int Nbase, _Float16* Xl0, _Float16* Xl1,
                                          f32x4 acc[4][4]) {
  const float* wb = Wg + (size_t)(lk * 8) * HD + Nbase + lrow;
  float wf[4][8];                       // current-step W f32 (prefetch depth 1)
  float4 xr[2];
  x_load(xs0, b0, n, 0, tid, xr);
#pragma unroll
  for (int nf = 0; nf < 4; ++nf)
#pragma unroll
    for (int j = 0; j < 8; ++j) wf[nf][j] = wb[j * HD + nf * 16];
  x_write(Xl0, tid, xr);
#pragma unroll 2
  for (int kt = 0; kt < NK; ++kt) {
    _Float16* Xc = (kt & 1) ? Xl1 : Xl0;
    _Float16* Xn = (kt & 1) ? Xl0 : Xl1;
    __syncthreads();                    // X buffer kt ready
    bool more = (kt + 1 < NK);
    if (more) {                         // X loads for kt+1 (oldest-first batch)
      int kOff = (kt + 1) * 32;
      const float* xs = (kOff < 256) ? xs0 : xs1;
      x_load(xs, b0, n, kOff & 255, tid, xr);
    }
    f16x8 b[4];                         // cvt current W (waits only W batch)
#pragma unroll
    for (int nf = 0; nf < 4; ++nf) b[nf] = pack8(wf[nf]);
    if (more) {                         // issue next-step W loads; they stay
      const float* wnx = wb + (size_t)(kt + 1) * 32 * HD;   // in flight across
#pragma unroll                                              // the next barrier
      for (int nf = 0; nf < 4; ++nf)
#pragma unroll
        for (int j = 0; j < 8; ++j) wf[nf][j] = wnx[j * HD + nf * 16];
    }
#pragma unroll
    for (int m = 0; m < 4; ++m) {
      f16x8 a = *(const f16x8*)(Xc + (m * 16 + lrow) * XS + lk * 8);
#pragma unroll
      for (int nf = 0; nf < 4; ++nf)
        acc[m][nf] = __builtin_amdgcn_mfma_f32_16x16x32_f16(a, b[nf], acc[m][nf], 0, 0, 0);
    }
    if (more) x_write(Xn, tid, xr);     // waits X batch only (W stays in flight)
  }
  __syncthreads();
}

// ---------- h epilogue: relu(C1 + b1) -> fp16 LDS [row][col] ----------
__device__ __forceinline__ void h_write(_Float16* hl, const float* __restrict__ b1g,
                                        int w, int lrow, int lk, const f32x4 acc[4][4]) {
#pragma unroll
  for (int nf = 0; nf < 4; ++nf) {
    int col = w * 64 + nf * 16 + lrow;
    float bv = b1g[col];
#pragma unroll
    for (int m = 0; m < 4; ++m)
#pragma unroll
      for (int r = 0; r < 4; ++r) {
        int row = m * 16 + lk * 4 + r;  // C/D: row=(l>>4)*4+reg, col=l&15
        hl[row * HS + col] = (_Float16)fmaxf(acc[m][nf][r] + bv, 0.f);
      }
  }
}

// ---------- GEMM2: C2(64x64) += h(64x256) @ W2(256x64) ----------
// wave-grid 2M x 2N. B-frags direct from global: W2[s*32+(l>>4)*8+j][wn*32+nf*16+(l&15)].
__device__ __forceinline__ void w2_load(const float* __restrict__ W2g, int wn, int lrow,
                                        int lk, int s, float wf[2][8]) {
  const float* wb = W2g + (size_t)(s * 32 + lk * 8) * FD + wn * 32 + lrow;
#pragma unroll
  for (int nf = 0; nf < 2; ++nf)
#pragma unroll
    for (int j = 0; j < 8; ++j) wf[nf][j] = wb[j * FD + nf * 16];
}

__device__ __forceinline__ void run_gemm2(const _Float16* hl, const float* __restrict__ W2g,
                                          int wm, int wn, int lrow, int lk,
                                          float wf[2][8], f32x4 acc2[2][2]) {
#pragma unroll 2
  for (int s = 0; s < 8; ++s) {
    f16x8 b[2];
    b[0] = pack8(wf[0]);
    b[1] = pack8(wf[1]);
    if (s < 7) w2_load(W2g, wn, lrow, lk, s + 1, wf);
#pragma unroll
    for (int mf = 0; mf < 2; ++mf) {
      f16x8 a = *(const f16x8*)(hl + (wm * 32 + mf * 16 + lrow) * HS + s * 32 + lk * 8);
#pragma unroll
      for (int nf = 0; nf < 2; ++nf)
        acc2[mf][nf] = __builtin_amdgcn_mfma_f32_16x16x32_f16(a, b[nf], acc2[mf][nf], 0, 0, 0);
    }
  }
}

__global__ __launch_bounds__(256, 3) void phase1_kernel(
    const float* __restrict__ obs, const float* __restrict__ act,
    const float* __restrict__ V_W1, const float* __restrict__ V_b1,
    const float* __restrict__ V_W2, const float* __restrict__ V_b2,
    const float* __restrict__ A_W1, const float* __restrict__ A_b1,
    const float* __restrict__ A_W2, const float* __restrict__ A_b2,
    float* __restrict__ Q) {
  __shared__ __align__(16) _Float16 Xl[2][64 * XS];   // 10.0 KB
  __shared__ __align__(16) _Float16 hl[64 * HS];      // 33.0 KB  => 44 KB, 3 blk/CU

  int tid = threadIdx.x;
  int l = tid & 63, w = tid >> 6;
  int lrow = l & 15, lk = l >> 4;
  int Nbase = w * 64;
  int wm = w >> 1, wn = w & 1;

  // all 4 b-blocks of a node share an XCD residue (weight L2 reuse)
  int bid = blockIdx.x;
  int r = bid & 7, s = bid >> 3;
  int n = r * 32 + (s & 31);
  int b0 = (s >> 5) * 64;

  f32x4 acc2[2][2];
#pragma unroll
  for (int i = 0; i < 2; ++i)
#pragma unroll
    for (int j = 0; j < 2; ++j) acc2[i][j] = (f32x4){0.f, 0.f, 0.f, 0.f};

  f32x4 acc[4][4];
  float wf2[2][8];

  // ---------------- V branch ----------------
#pragma unroll
  for (int m = 0; m < 4; ++m)
#pragma unroll
    for (int nf = 0; nf < 4; ++nf) acc[m][nf] = (f32x4){0.f, 0.f, 0.f, 0.f};
  run_gemm1<8>(obs, obs, V_W1 + (size_t)n * HD * HD, b0, n, tid, lrow, lk, Nbase,
               Xl[0], Xl[1], acc);
  h_write(hl, V_b1 + n * HD, w, lrow, lk, acc);
  w2_load(V_W2 + (size_t)n * HD * FD, wn, lrow, lk, 0, wf2);  // hides under barrier
  __syncthreads();                      // hl published
  run_gemm2(hl, V_W2 + (size_t)n * HD * FD, wm, wn, lrow, lk, wf2, acc2);

  // ---------------- A branch ----------------
#pragma unroll
  for (int m = 0; m < 4; ++m)
#pragma unroll
    for (int nf = 0; nf < 4; ++nf) acc[m][nf] = (f32x4){0.f, 0.f, 0.f, 0.f};
  run_gemm1<16>(obs, act, A_W1 + (size_t)n * 2 * HD * HD, b0, n, tid, lrow, lk, Nbase,
                Xl[0], Xl[1], acc);
  h_write(hl, A_b1 + n * HD, w, lrow, lk, acc);
  w2_load(A_W2 + (size_t)n * HD * FD, wn, lrow, lk, 0, wf2);
  __syncthreads();
  run_gemm2(hl, A_W2 + (size_t)n * HD * FD, wm, wn, lrow, lk, wf2, acc2);

  // ---------------- Q = acc2 + V_b2 + A_b2 ----------------
  const float* vb2 = V_b2 + n * FD;
  const float* ab2 = A_b2 + n * FD;
#pragma unroll
  for (int mf = 0; mf < 2; ++mf)
#pragma unroll
    for (int nf = 0; nf < 2; ++nf) {
      int f = wn * 32 + nf * 16 + lrow;
      float bias = vb2[f] + ab2[f];
#pragma unroll
      for (int rr = 0; rr < 4; ++rr) {
        int row = b0 + wm * 32 + mf * 16 + lk * 4 + rr;
        Q[(size_t)row * (BN * FD) + n * FD + f] = acc2[mf][nf][rr] + bias;
      }
    }
}

// ---------------- phase 2: gather + subset-min + chi + mean ----------------
__global__ __launch_bounds__(256) void phase2_kernel(const float* __restrict__ Q,
                                                     const float* __restrict__ chi_m,
                                                     const int* __restrict__ le,
                                                     float* __restrict__ out) {
  int b = blockIdx.x;
  int n = threadIdx.x;
  // int64-vs-int32 layout hedge: centers = arange(N) => int32 layout has le[5]==1.
  int step = (le[5] == 1) ? 1 : 2;
  const int* e = le + n * 5 * step;
  int c  = e[0 * step] & (BN - 1);
  int n0 = e[1 * step] & (BN - 1);
  int n1 = e[2 * step] & (BN - 1);
  int n2 = e[3 * step] & (BN - 1);
  int n3 = e[4 * step] & (BN - 1);
  const float* ch = chi_m + n * 45;     // (HEADS=3, S=15)
  float cm[15];
#pragma unroll
  for (int s = 0; s < 15; ++s) cm[s] = (ch[s] + ch[15 + s] + ch[30 + s]) * (1.f / 3.f);
  const float* qb = Q + (size_t)b * (BN * FD);
  const float* q0 = qb + n0 * FD;
  const float* q1 = qb + n1 * FD;
  const float* q2 = qb + n2 * FD;
  const float* q3 = qb + n3 * FD;
  const float* qc = qb + c * FD;
  float acc = 0.f;
#pragma unroll
  for (int f = 0; f < FD; f += 4) {
    float4 v0 = *(const float4*)(q0 + f);
    float4 v1 = *(const float4*)(q1 + f);
    float4 v2 = *(const float4*)(q2 + f);
    float4 v3 = *(const float4*)(q3 + f);
    float4 vc = *(const float4*)(qc + f);
    const float* p0 = (const float*)&v0;
    const float* p1 = (const float*)&v1;
    const float* p2 = (const float*)&v2;
    const float* p3 = (const float*)&v3;
    const float* pc = (const float*)&vc;
#pragma unroll
    for (int u = 0; u < 4; ++u) {
      float a = p0[u], bq = p1[u], cq = p2[u], d = p3[u];
      float m01 = fminf(a, bq), m02 = fminf(a, cq), m03 = fminf(a, d);
      float m12 = fminf(bq, cq), m13 = fminf(bq, d), m23 = fminf(cq, d);
      float m012 = fminf(m01, cq), m013 = fminf(m01, d);
      float m023 = fminf(m02, d),  m123 = fminf(m12, d);
      float m0123 = fminf(m01, m23);
      float chi = cm[0] * a   + cm[1] * bq   + cm[2] * m01  + cm[3] * cq
                + cm[4] * m02 + cm[5] * m12  + cm[6] * m012 + cm[7] * d
                + cm[8] * m03 + cm[9] * m13  + cm[10] * m013 + cm[11] * m23
                + cm[12] * m023 + cm[13] * m123 + cm[14] * m0123;
      acc += chi + pc[u];
    }
  }
  out[b * BN + n] = acc * (1.f / 64.f);
}

extern "C" void kernel_launch(void* const* d_in, const int* in_sizes, int n_in,
                              void* d_out, int out_size, void* d_ws, size_t ws_size,
                              hipStream_t stream) {
  (void)in_sizes; (void)n_in; (void)out_size; (void)ws_size;
  const float* obs  = (const float*)d_in[0];
  const float* act  = (const float*)d_in[1];
  const float* V_W1 = (const float*)d_in[2];
  const float* V_b1 = (const float*)d_in[3];
  const float* V_W2 = (const float*)d_in[4];
  const float* V_b2 = (const float*)d_in[5];
  const float* A_W1 = (const float*)d_in[6];
  const float* A_b1 = (const float*)d_in[7];
  const float* A_W2 = (const float*)d_in[8];
  const float* A_b2 = (const float*)d_in[9];
  const float* chim = (const float*)d_in[10];
  const int*   le   = (const int*)d_in[11];
  float* Q   = (float*)d_ws;            // 16 MB scratch: Q[B][N][F]
  float* out = (float*)d_out;

  phase1_kernel<<<dim3(1024), dim3(256), 0, stream>>>(obs, act, V_W1, V_b1, V_W2, V_b2,
                                                      A_W1, A_b1, A_W2, A_b2, Q);
  phase2_kernel<<<dim3(256), dim3(256), 0, stream>>>(Q, chim, le, out);
}

// Round 5
// 174.238 us; speedup vs baseline: 1.0641x; 1.0641x over previous
//
#include <hip/hip_runtime.h>
#include <cstddef>

// Critic_43104291783486 — round 5: depth-2 prefetch pipelines (explicit even/odd
// register batches, no dynamic indexing), launch_bounds(256,2) so the compiler
// keeps full load batches in flight (r4's (256,3)/VGPR=84 chunked them).
// Structure otherwise = r4: W direct global->reg B-frags, X LDS-staged fp16,
// v_mfma_f32_16x16x32_f16, f32 accumulate.

#define BN 256   // nodes
#define HD 256   // hidden
#define FD 64    // feature out

#define XS 40    // X lds row stride (fp16): 32 k + 8 pad (80B rows, 16B aligned)
#define HS 264   // h lds row stride (fp16): 256 + 8 pad (528B rows)

typedef _Float16 f16x8 __attribute__((ext_vector_type(8)));
typedef float f32x4 __attribute__((ext_vector_type(4)));

__device__ __forceinline__ f16x8 pack8(const float v[8]) {
  f16x8 r;
#pragma unroll
  for (int i = 0; i < 8; ++i) r[i] = (_Float16)v[i];
  return r;
}

// ---------- X staging: 64 rows x 32 k, fp32 global -> fp16 LDS ----------
// thread t: row = t>>2, k-oct = (t&3)*8; 4 lanes cover 128B contiguous global.
__device__ __forceinline__ void x_load(const float* __restrict__ src, int b0, int n,
                                       int kOff, int tid, float4 xr[2]) {
  int row = tid >> 2, ko = (tid & 3) * 8;
  const float* p = src + (size_t)(b0 + row) * (BN * HD) + n * HD + kOff + ko;
  xr[0] = *(const float4*)p;
  xr[1] = *(const float4*)(p + 4);
}
__device__ __forceinline__ void x_loadk(const float* xs0, const float* xs1, int b0,
                                        int n, int kt, int tid, float4 xr[2]) {
  int kOff = kt * 32;
  const float* xs = (kOff < 256) ? xs0 : xs1;   // A-branch switches obs->act at k=256
  x_load(xs, b0, n, kOff & 255, tid, xr);
}
__device__ __forceinline__ void x_write(_Float16* Xl, int tid, const float4 xr[2]) {
  int row = tid >> 2, ko = (tid & 3) * 8;
  const float* f = (const float*)xr;
  f16x8 v;
#pragma unroll
  for (int i = 0; i < 8; ++i) v[i] = (_Float16)f[i];
  *(f16x8*)(Xl + row * XS + ko) = v;   // 16B-aligned (XS*2 = 80)
}

// ---------- W1 B-fragment batch: 4 frags x 8 dwords, stride HD ----------
__device__ __forceinline__ void w1_load(const float* __restrict__ wb, float wf[4][8]) {
#pragma unroll
  for (int nf = 0; nf < 4; ++nf)
#pragma unroll
    for (int j = 0; j < 8; ++j) wf[nf][j] = wb[(size_t)j * HD + nf * 16];
}

// ---------- GEMM1: C(64x256) = X(64xK) @ W(Kx256), K = NK*32, NK even ----------
// wave w owns cols w*64..+63. B-frag elem j (lane l): W[kt*32+(l>>4)*8+j][Nbase+nf*16+(l&15)].
// A-frag (LDS): row = m*16 + (l&15), k contiguous. Layouts verified r3/r4.
// Depth-2: wfA/xrA hold even-kt data, wfB/xrB odd-kt; reloaded with kt+2 in-step.
#define G1_STEP(KT, WFC, XRC, XRN, XLC, XLN)                                       \
  {                                                                                \
    __syncthreads();                      /* XLC fully written by all waves */     \
    const int kt_ = (KT);                                                          \
    f16x8 bfr[4];                         /* cvt waits batch issued at kt-2 */     \
    _Pragma("unroll") for (int nf = 0; nf < 4; ++nf) bfr[nf] = pack8(WFC[nf]);     \
    if (kt_ + 2 < NK) {                   /* reload freed batches with kt+2 */     \
      w1_load(wb + (size_t)(kt_ + 2) * 32 * HD, WFC);                              \
      x_loadk(xs0, xs1, b0, n, kt_ + 2, tid, XRC);                                 \
    }                                                                              \
    _Pragma("unroll") for (int m = 0; m < 4; ++m) {                                \
      f16x8 a = *(const f16x8*)(XLC + (m * 16 + lrow) * XS + lk * 8);              \
      _Pragma("unroll") for (int nf = 0; nf < 4; ++nf)                             \
        acc[m][nf] =                                                               \
            __builtin_amdgcn_mfma_f32_16x16x32_f16(a, bfr[nf], acc[m][nf], 0, 0, 0); \
    }                                                                              \
    if (kt_ + 1 < NK) x_write(XLN, tid, XRN);  /* XRN issued at kt-1 */            \
  }

template <int NK>
__device__ __forceinline__ void run_gemm1(const float* xs0, const float* xs1,
                                          const float* __restrict__ Wg,
                                          int b0, int n, int tid, int lrow, int lk,
                                          int Nbase, _Float16* Xl0, _Float16* Xl1,
                                          f32x4 acc[4][4]) {
  const float* wb = Wg + (size_t)(lk * 8) * HD + Nbase + lrow;
  float wfA[4][8], wfB[4][8];
  float4 xrA[2], xrB[2];
  // prologue: kt=0 and kt=1 batches all in flight
  x_loadk(xs0, xs1, b0, n, 0, tid, xrA);
  w1_load(wb, wfA);
  x_loadk(xs0, xs1, b0, n, 1, tid, xrB);
  w1_load(wb + (size_t)32 * HD, wfB);
  x_write(Xl0, tid, xrA);                 // waits only oldest (xrA) batch
#pragma unroll 1
  for (int kt = 0; kt < NK; kt += 2) {
    G1_STEP(kt,     wfA, xrA, xrB, Xl0, Xl1)
    G1_STEP(kt + 1, wfB, xrB, xrA, Xl1, Xl0)
  }
  __syncthreads();                        // all X reads done before next use
}

// ---------- h epilogue: relu(C1 + b1) -> fp16 LDS [row][col] ----------
__device__ __forceinline__ void h_write(_Float16* hl, const float* __restrict__ b1g,
                                        int w, int lrow, int lk, const f32x4 acc[4][4]) {
#pragma unroll
  for (int nf = 0; nf < 4; ++nf) {
    int col = w * 64 + nf * 16 + lrow;
    float bv = b1g[col];
#pragma unroll
    for (int m = 0; m < 4; ++m)
#pragma unroll
      for (int r = 0; r < 4; ++r) {
        int row = m * 16 + lk * 4 + r;    // C/D: row=(l>>4)*4+reg, col=l&15
        hl[row * HS + col] = (_Float16)fmaxf(acc[m][nf][r] + bv, 0.f);
      }
  }
}

// ---------- GEMM2: C2(64x64) += h(64x256) @ W2(256x64), depth-2 ----------
__device__ __forceinline__ void w2_load(const float* __restrict__ W2g, int wn, int lrow,
                                        int lk, int s, float wf[2][8]) {
  const float* wb = W2g + (size_t)(s * 32 + lk * 8) * FD + wn * 32 + lrow;
#pragma unroll
  for (int nf = 0; nf < 2; ++nf)
#pragma unroll
    for (int j = 0; j < 8; ++j) wf[nf][j] = wb[j * FD + nf * 16];
}

#define G2_STEP(S, WFC)                                                            \
  {                                                                                \
    const int s_ = (S);                                                            \
    f16x8 bf0 = pack8(WFC[0]), bf1 = pack8(WFC[1]);                                \
    if (s_ + 2 < 8) w2_load(W2g, wn, lrow, lk, s_ + 2, WFC);                       \
    _Pragma("unroll") for (int mf = 0; mf < 2; ++mf) {                             \
      f16x8 a = *(const f16x8*)(hl + (wm * 32 + mf * 16 + lrow) * HS + s_ * 32 + lk * 8); \
      acc2[mf][0] = __builtin_amdgcn_mfma_f32_16x16x32_f16(a, bf0, acc2[mf][0], 0, 0, 0); \
      acc2[mf][1] = __builtin_amdgcn_mfma_f32_16x16x32_f16(a, bf1, acc2[mf][1], 0, 0, 0); \
    }                                                                              \
  }

__global__ __launch_bounds__(256, 2) void phase1_kernel(
    const float* __restrict__ obs, const float* __restrict__ act,
    const float* __restrict__ V_W1, const float* __restrict__ V_b1,
    const float* __restrict__ V_W2, const float* __restrict__ V_b2,
    const float* __restrict__ A_W1, const float* __restrict__ A_b1,
    const float* __restrict__ A_W2, const float* __restrict__ A_b2,
    float* __restrict__ Q) {
  __shared__ __align__(16) _Float16 Xl[2][64 * XS];   // 10.0 KB
  __shared__ __align__(16) _Float16 hl[64 * HS];      // 33.0 KB => 44 KB total

  int tid = threadIdx.x;
  int l = tid & 63, w = tid >> 6;
  int lrow = l & 15, lk = l >> 4;
  int Nbase = w * 64;
  int wm = w >> 1, wn = w & 1;

  // all 4 b-blocks of a node share an XCD residue (weight L2/L3 reuse)
  int bid = blockIdx.x;
  int r = bid & 7, s = bid >> 3;
  int n = r * 32 + (s & 31);
  int b0 = (s >> 5) * 64;

  f32x4 acc2[2][2];
#pragma unroll
  for (int i = 0; i < 2; ++i)
#pragma unroll
    for (int j = 0; j < 2; ++j) acc2[i][j] = (f32x4){0.f, 0.f, 0.f, 0.f};

  f32x4 acc[4][4];
  float wfA2[2][8], wfB2[2][8];

  // ---------------- V branch ----------------
#pragma unroll
  for (int m = 0; m < 4; ++m)
#pragma unroll
    for (int nf = 0; nf < 4; ++nf) acc[m][nf] = (f32x4){0.f, 0.f, 0.f, 0.f};
  run_gemm1<8>(obs, obs, V_W1 + (size_t)n * HD * HD, b0, n, tid, lrow, lk, Nbase,
               Xl[0], Xl[1], acc);
  {
    const float* W2g = V_W2 + (size_t)n * HD * FD;
    w2_load(W2g, wn, lrow, lk, 0, wfA2);  // both prologue batches fly under
    w2_load(W2g, wn, lrow, lk, 1, wfB2);  // h_write + the hl-publish barrier
    h_write(hl, V_b1 + n * HD, w, lrow, lk, acc);
    __syncthreads();                      // hl published
#pragma unroll 1
    for (int s2 = 0; s2 < 8; s2 += 2) {
      G2_STEP(s2,     wfA2)
      G2_STEP(s2 + 1, wfB2)
    }
    __syncthreads();                      // hl reads done before A overwrites
  }

  // ---------------- A branch ----------------
#pragma unroll
  for (int m = 0; m < 4; ++m)
#pragma unroll
    for (int nf = 0; nf < 4; ++nf) acc[m][nf] = (f32x4){0.f, 0.f, 0.f, 0.f};
  run_gemm1<16>(obs, act, A_W1 + (size_t)n * 2 * HD * HD, b0, n, tid, lrow, lk, Nbase,
                Xl[0], Xl[1], acc);
  {
    const float* W2g = A_W2 + (size_t)n * HD * FD;
    w2_load(W2g, wn, lrow, lk, 0, wfA2);
    w2_load(W2g, wn, lrow, lk, 1, wfB2);
    h_write(hl, A_b1 + n * HD, w, lrow, lk, acc);
    __syncthreads();
#pragma unroll 1
    for (int s2 = 0; s2 < 8; s2 += 2) {
      G2_STEP(s2,     wfA2)
      G2_STEP(s2 + 1, wfB2)
    }
  }

  // ---------------- Q = acc2 + V_b2 + A_b2 ----------------
  const float* vb2 = V_b2 + n * FD;
  const float* ab2 = A_b2 + n * FD;
#pragma unroll
  for (int mf = 0; mf < 2; ++mf)
#pragma unroll
    for (int nf = 0; nf < 2; ++nf) {
      int f = wn * 32 + nf * 16 + lrow;
      float bias = vb2[f] + ab2[f];
#pragma unroll
      for (int rr = 0; rr < 4; ++rr) {
        int row = b0 + wm * 32 + mf * 16 + lk * 4 + rr;
        Q[(size_t)row * (BN * FD) + n * FD + f] = acc2[mf][nf][rr] + bias;
      }
    }
}

// ---------------- phase 2: gather + subset-min + chi + mean ----------------
__global__ __launch_bounds__(256) void phase2_kernel(const float* __restrict__ Q,
                                                     const float* __restrict__ chi_m,
                                                     const int* __restrict__ le,
                                                     float* __restrict__ out) {
  int b = blockIdx.x;
  int n = threadIdx.x;
  // int64-vs-int32 layout hedge: centers = arange(N) => int32 layout has le[5]==1.
  int step = (le[5] == 1) ? 1 : 2;
  const int* e = le + n * 5 * step;
  int c  = e[0 * step] & (BN - 1);
  int n0 = e[1 * step] & (BN - 1);
  int n1 = e[2 * step] & (BN - 1);
  int n2 = e[3 * step] & (BN - 1);
  int n3 = e[4 * step] & (BN - 1);
  const float* ch = chi_m + n * 45;     // (HEADS=3, S=15)
  float cm[15];
#pragma unroll
  for (int s = 0; s < 15; ++s) cm[s] = (ch[s] + ch[15 + s] + ch[30 + s]) * (1.f / 3.f);
  const float* qb = Q + (size_t)b * (BN * FD);
  const float* q0 = qb + n0 * FD;
  const float* q1 = qb + n1 * FD;
  const float* q2 = qb + n2 * FD;
  const float* q3 = qb + n3 * FD;
  const float* qc = qb + c * FD;
  float acc = 0.f;
#pragma unroll
  for (int f = 0; f < FD; f += 4) {
    float4 v0 = *(const float4*)(q0 + f);
    float4 v1 = *(const float4*)(q1 + f);
    float4 v2 = *(const float4*)(q2 + f);
    float4 v3 = *(const float4*)(q3 + f);
    float4 vc = *(const float4*)(qc + f);
    const float* p0 = (const float*)&v0;
    const float* p1 = (const float*)&v1;
    const float* p2 = (const float*)&v2;
    const float* p3 = (const float*)&v3;
    const float* pc = (const float*)&vc;
#pragma unroll
    for (int u = 0; u < 4; ++u) {
      float a = p0[u], bq = p1[u], cq = p2[u], d = p3[u];
      float m01 = fminf(a, bq), m02 = fminf(a, cq), m03 = fminf(a, d);
      float m12 = fminf(bq, cq), m13 = fminf(bq, d), m23 = fminf(cq, d);
      float m012 = fminf(m01, cq), m013 = fminf(m01, d);
      float m023 = fminf(m02, d),  m123 = fminf(m12, d);
      float m0123 = fminf(m01, m23);
      float chi = cm[0] * a   + cm[1] * bq   + cm[2] * m01  + cm[3] * cq
                + cm[4] * m02 + cm[5] * m12  + cm[6] * m012 + cm[7] * d
                + cm[8] * m03 + cm[9] * m13  + cm[10] * m013 + cm[11] * m23
                + cm[12] * m023 + cm[13] * m123 + cm[14] * m0123;
      acc += chi + pc[u];
    }
  }
  out[b * BN + n] = acc * (1.f / 64.f);
}

extern "C" void kernel_launch(void* const* d_in, const int* in_sizes, int n_in,
                              void* d_out, int out_size, void* d_ws, size_t ws_size,
                              hipStream_t stream) {
  (void)in_sizes; (void)n_in; (void)out_size; (void)ws_size;
  const float* obs  = (const float*)d_in[0];
  const float* act  = (const float*)d_in[1];
  const float* V_W1 = (const float*)d_in[2];
  const float* V_b1 = (const float*)d_in[3];
  const float* V_W2 = (const float*)d_in[4];
  const float* V_b2 = (const float*)d_in[5];
  const float* A_W1 = (const float*)d_in[6];
  const float* A_b1 = (const float*)d_in[7];
  const float* A_W2 = (const float*)d_in[8];
  const float* A_b2 = (const float*)d_in[9];
  const float* chim = (const float*)d_in[10];
  const int*   le   = (const int*)d_in[11];
  float* Q   = (float*)d_ws;            // 16 MB scratch: Q[B][N][F]
  float* out = (float*)d_out;

  phase1_kernel<<<dim3(1024), dim3(256), 0, stream>>>(obs, act, V_W1, V_b1, V_W2, V_b2,
                                                      A_W1, A_b1, A_W2, A_b2, Q);
  phase2_kernel<<<dim3(256), dim3(256), 0, stream>>>(Q, chim, le, out);
}